// Round 8
// baseline (566.657 us; speedup 1.0000x reference)
//
#include <hip/hip_runtime.h>
#include <math.h>

#define RQ 6              // per-lane queue depth; P(lane owns >6 of global top-24) ~0.3 events/run
constexpr int TPW = 8;    // (query,list) tasks per wave in knn

typedef __attribute__((ext_vector_type(8))) short s8v;    // 8 bf16 (4 VGPRs)
typedef __attribute__((ext_vector_type(4))) float f32x4;  // MFMA acc

__device__ inline unsigned short f2bf(float x) {          // RNE f32->bf16
    const unsigned int u = __float_as_uint(x);
    return (unsigned short)((u + 0x7FFFu + ((u >> 16) & 1u)) >> 16);
}

// ---------------------------------------------------------------------------
// K0: per-(sample,list) z-sort. One 1024-thr block per (b,list): bitonic sort
// of (zkey<<32|idx) in LDS, then gather coords -> sp[] = float4(x,y,z,|p|^2)
// in ascending-z order.
// ---------------------------------------------------------------------------
__global__ __launch_bounds__(1024) void zsort_kernel(
    const float* __restrict__ p0, const float* __restrict__ p1,
    float4* __restrict__ sp, int N)
{
    __shared__ unsigned long long arr[4096];
    const int t = threadIdx.x;
    const int b = blockIdx.x >> 1, list = blockIdx.x & 1;
    const float* rb = (list ? p1 : p0) + (size_t)(b * 3) * N;
    for (int i = t; i < 4096; i += 1024) {
        const unsigned int u = __float_as_uint(rb[2 * N + i]);
        const unsigned int key = u ^ ((u >> 31) ? 0xFFFFFFFFu : 0x80000000u);
        arr[i] = ((unsigned long long)key << 32) | (unsigned int)i;
    }
    __syncthreads();
    for (int k = 2; k <= 4096; k <<= 1)
        for (int jj = k >> 1; jj > 0; jj >>= 1) {
            for (int i = t; i < 4096; i += 1024) {
                const int ixj = i ^ jj;
                if (ixj > i) {
                    const unsigned long long a = arr[i], c = arr[ixj];
                    if ((a > c) == ((i & k) == 0)) { arr[i] = c; arr[ixj] = a; }
                }
            }
            __syncthreads();
        }
    for (int i = t; i < 4096; i += 1024) {
        const int oi = (int)(arr[i] & 0xFFFFFFFFu);
        const float x = rb[oi], y = rb[N + oi], z = rb[2 * N + oi];
        sp[(size_t)blockIdx.x * 4096 + i] =
            make_float4(x, y, z, fmaf(x, x, fmaf(y, y, z * z)));
    }
}

// ---------------------------------------------------------------------------
// K1: exact kNN with z-window pruning. Wave per (query,list) task, no LDS, no
// barriers. Two 64-way ballot probes locate the query's z-rank; chunks of 64
// z-sorted candidates expand outward (nearer-frontier direction first).
// Bound B = max over lanes 0..31 of per-lane queue-min: >=32 real candidates
// <= B => kk-th smallest <= B (kk<=24), so stopping a direction when the
// frontier dz^2 > B is EXACT. Queue/extraction semantics identical to the
// verified round-6 kernel (sorted top-6 u32 key/idx, stable insert, butterfly
// min + smallest-index tiebreak).
// ---------------------------------------------------------------------------
__global__ __launch_bounds__(256) void knn_kernel(
    const float* __restrict__ p0, const float* __restrict__ p1,
    const float* __restrict__ wt, const int* __restrict__ perm,
    const float4* __restrict__ sp,
    float4* __restrict__ feat, float4* __restrict__ newp, int N)
{
    const int lane = threadIdx.x & 63;
    const int gwave = (int)((blockIdx.x * 256 + threadIdx.x) >> 6);

    for (int ti = 0; ti < TPW; ++ti) {
        const int task = gwave * TPW + ti;
        const int b = task / (2 * N);
        const int rem = task - b * 2 * N;
        const int list = rem / N;
        const int n = rem - list * N;
        const int q = b * N + n;

        const float wt0 = wt[b * 2];
        const int N0 = (int)(N * wt0);
        const int k0 = (int)(32 * wt0);
        const int kk = list ? (32 - k0) : k0;     // in [8,24]

        int j; const float* src;
        if (n < N0) { j = perm[(b * 2) * N + n];            src = p0; }
        else        { j = perm[(b * 2 + 1) * N + (n - N0)]; src = p1; }
        const float qx = __uint_as_float(__builtin_amdgcn_readfirstlane(
                             __float_as_uint(src[(b * 3) * N + j])));
        const float qy = __uint_as_float(__builtin_amdgcn_readfirstlane(
                             __float_as_uint(src[(b * 3 + 1) * N + j])));
        const float qz = __uint_as_float(__builtin_amdgcn_readfirstlane(
                             __float_as_uint(src[(b * 3 + 2) * N + j])));
        const float qq = qx * qx + qy * qy + qz * qz;

        const float4* L = sp + (size_t)(b * 2 + list) * 4096;

        // two-level 64-way probe: c = insertion rank of qz in sorted z
        const float zs = L[lane << 6].z;
        const int cnt1 = __popcll(__ballot(zs <= qz));
        const int base1 = (cnt1 > 0 ? cnt1 - 1 : 0) << 6;
        const float z2 = L[base1 + lane].z;
        const int cnt2 = __popcll(__ballot(z2 <= qz));
        const int c = base1 + cnt2;

        unsigned int kh[RQ], kl[RQ];
#pragma unroll
        for (int s = 0; s < RQ; ++s) { kh[s] = 0xFFFFFFFFu; kl[s] = 0xFFFFFFFFu; }

        int r = c, lft = c - 1;
        float dzR2 = 0.f, dzL2 = 0.f;
        bool aliveR = (r <= 4095), aliveL = (lft >= 0);
        float B_f = __uint_as_float(0xFFFFFFFFu);   // NaN: "no bound yet"

        while (aliveR || aliveL) {
            const bool doR = aliveR && (!aliveL || !(dzL2 < dzR2));
            const int base = doR ? r : (lft - 63);
            const int pos = base + lane;
            const bool valid = ((unsigned)pos < 4096u);
            const float4 pc = L[valid ? pos : 0];
            float dt = fmaf(qz, pc.z, fmaf(qy, pc.y, qx * pc.x));
            const float d = fmaxf(fmaf(-2.f, dt, pc.w + qq), 0.f);
            const unsigned int key = valid ? __float_as_uint(d) : 0xFFFFFFFFu;

            bool cb[RQ];
#pragma unroll
            for (int s = 0; s < RQ; ++s) cb[s] = key < kh[s];
#pragma unroll
            for (int s = RQ - 1; s >= 1; --s) {
                kh[s] = cb[s - 1] ? kh[s - 1] : (cb[s] ? key : kh[s]);
                kl[s] = cb[s - 1] ? kl[s - 1] : (cb[s] ? (unsigned int)pos : kl[s]);
            }
            kh[0] = cb[0] ? key : kh[0];
            kl[0] = cb[0] ? (unsigned int)pos : kl[0];

            // bound: max over lanes 0..31 of queue-min (sentinel -> NaN -> no kill)
            unsigned int bb = kh[0];
#pragma unroll
            for (int off = 1; off <= 16; off <<= 1) {
                const unsigned int o = __shfl_xor(bb, off);
                bb = bb > o ? bb : o;
            }
            B_f = __uint_as_float(__builtin_amdgcn_readfirstlane(bb));

            if (doR) {
                const float pz = __shfl(pc.z, 63);   // last scanned z (proxy)
                r = base + 64;
                const float dz = pz - qz;
                dzR2 = dz * dz * 0.99999f;           // conservative rounding slack
                aliveR = (r <= 4095) && !(dzR2 > B_f);
            } else {
                const float pz = __shfl(pc.z, 0);
                lft = base - 1;
                const float dz = pz - qz;
                dzL2 = dz * dz * 0.99999f;
                aliveL = (lft >= 0) && !(dzL2 > B_f);
            }
        }

        // extract: kk rounds of key wave-min + exact smallest-idx tiebreak
        unsigned int mwin = 0;
        for (int rr = 0; rr < kk; ++rr) {
            unsigned int g = kh[0];
#pragma unroll
            for (int off = 32; off; off >>= 1) g = min(g, __shfl_xor(g, off));
            const bool tied = (kh[0] == g);
            unsigned int mc;
            const unsigned long long bal = __ballot(tied);
            if (bal & (bal - 1)) {
                mc = tied ? kl[0] : 0xFFFFFFFFu;
#pragma unroll
                for (int off = 32; off; off >>= 1) mc = min(mc, __shfl_xor(mc, off));
            } else {
                mc = __shfl(kl[0], (int)__ffsll((long long)bal) - 1);
            }
            const bool w = tied && (kl[0] == mc);
            if (lane == rr) mwin = mc;
#pragma unroll
            for (int s = 0; s < RQ - 1; ++s) {
                kh[s] = w ? kh[s + 1] : kh[s];
                kl[s] = w ? kl[s + 1] : kl[s];
            }
            kh[RQ - 1] = w ? 0xFFFFFFFFu : kh[RQ - 1];
            kl[RQ - 1] = w ? 0xFFFFFFFFu : kl[RQ - 1];
        }
        const int obase = (q << 5) + (list ? k0 : 0);
        if (lane < kk) {
            const float4 pc = L[mwin];
            const float rx = pc.x - qx, ry = pc.y - qy, rz = pc.z - qz;
            feat[obase + lane] =
                make_float4(rx, ry, rz,
                            sqrtf(fmaf(rx, rx, fmaf(ry, ry, rz * rz))));
        }
        if (list == 0 && lane == 0) newp[q] = make_float4(qx, qy, qz, 0.f);
    }
}

// ---------------------------------------------------------------------------
// K2: per-sample feature moments (S=sum f [4], M=sum f f^T [10]).
// ---------------------------------------------------------------------------
__global__ __launch_bounds__(256) void moment_stats_kernel(
    const float4* __restrict__ feat, float* __restrict__ stats1, int N)
{
    const int t = threadIdx.x, lane = t & 63;
    const int bpb = 64;
    const int b = blockIdx.x / bpb;
    const int ppb = (N * 32) / bpb;
    const size_t base = (size_t)b * N * 32 + (size_t)(blockIdx.x % bpb) * ppb;
    float a[14];
#pragma unroll
    for (int i = 0; i < 14; ++i) a[i] = 0.f;
    for (int i = t; i < ppb; i += 256) {
        const float4 f = feat[base + i];
        a[0] += f.x; a[1] += f.y; a[2] += f.z; a[3] += f.w;
        a[4] = fmaf(f.x, f.x, a[4]);  a[5] = fmaf(f.x, f.y, a[5]);
        a[6] = fmaf(f.x, f.z, a[6]);  a[7] = fmaf(f.x, f.w, a[7]);
        a[8] = fmaf(f.y, f.y, a[8]);  a[9] = fmaf(f.y, f.z, a[9]);
        a[10] = fmaf(f.y, f.w, a[10]); a[11] = fmaf(f.z, f.z, a[11]);
        a[12] = fmaf(f.z, f.w, a[12]); a[13] = fmaf(f.w, f.w, a[13]);
    }
#pragma unroll
    for (int i = 0; i < 14; ++i) {
        float x = a[i];
#pragma unroll
        for (int o = 32; o; o >>= 1) x += __shfl_down(x, o);
        a[i] = x;
    }
    __shared__ float sm[14];
    if (t < 14) sm[t] = 0.f;
    __syncthreads();
    if (lane == 0) {
#pragma unroll
        for (int i = 0; i < 14; ++i) atomicAdd(&sm[i], a[i]);
    }
    __syncthreads();
    if (t < 14) atomicAdd(&stats1[b * 14 + t], sm[t]);
}

// ---------------------------------------------------------------------------
// K3/K4: conv1+gn1+relu -> bf16 h in LDS -> conv2 via MFMA 16x16x32
// (unchanged from round 7).
// ---------------------------------------------------------------------------
template <int MODE>
__global__ __launch_bounds__(256) void conv2_pass_kernel(
    const float4* __restrict__ feat,
    const float* __restrict__ w1, const float* __restrict__ b1,
    const float* __restrict__ gn1w, const float* __restrict__ gn1b,
    const float* __restrict__ stats1,
    const float* __restrict__ w2, const float* __restrict__ b2,
    const float* __restrict__ gn2w, const float* __restrict__ gn2b,
    float* __restrict__ stats2,
    const float4* __restrict__ newp, float* __restrict__ out,
    int N, float inv_cnt)
{
    const int t = threadIdx.x, lane = t & 63, wv = t >> 6;
    const int quad = lane >> 4, col = lane & 15;
    const int bpb = (N * 32) / 512;
    const int b = blockIdx.x / bpb;
    const int pblock = (blockIdx.x - b * bpb) * 512;
    const size_t pbase = (size_t)b * N * 32 + pblock + wv * 128;

    __shared__ float sfin[24];
    __shared__ float sacc[16];
    __shared__ unsigned short h_lds[512 * 40];
    __shared__ float ssc[512];

    if (t < 16) sacc[t] = 0.f;
    if (t < 4) {
        const float cnt = (float)(N * 32);
        const float* mm = stats1 + b * 14;
        const float S0 = mm[0], S1 = mm[1], S2 = mm[2], S3 = mm[3];
        float sum = 0.f, sq = 0.f;
        for (int cch = 0; cch < 8; ++cch) {
            const int cid = t * 8 + cch;
            const float4 w = ((const float4*)w1)[cid];
            const float bb = b1[cid];
            const float ws = w.x * S0 + w.y * S1 + w.z * S2 + w.w * S3;
            const float wMw =
                w.x * w.x * mm[4] + w.y * w.y * mm[8] + w.z * w.z * mm[11] +
                w.w * w.w * mm[13] +
                2.f * (w.x * w.y * mm[5] + w.x * w.z * mm[6] + w.x * w.w * mm[7] +
                       w.y * w.z * mm[9] + w.y * w.w * mm[10] + w.z * w.w * mm[12]);
            sum += cnt * bb + ws;
            sq += cnt * bb * bb + 2.f * bb * ws + wMw;
        }
        const float mu = sum * inv_cnt, var = sq * inv_cnt - mu * mu;
        sfin[2 * t] = mu; sfin[2 * t + 1] = rsqrtf(var + 1e-5f);
    }
    if (MODE == 1 && t >= 4 && t < 12) {
        const int g = t - 4;
        const float S = stats2[b * 16 + g], Q = stats2[b * 16 + 8 + g];
        const float mu = S * inv_cnt, var = Q * inv_cnt - mu * mu;
        sfin[8 + 2 * g] = mu; sfin[8 + 2 * g + 1] = rsqrtf(var + 1e-5f);
    }
    __syncthreads();

    const int c1 = lane & 31, pt = lane >> 5;
    const float4 w1r = ((const float4*)w1)[c1];
    const float b1c = b1[c1];
    const int g1 = c1 >> 3;
    const float sc1 = sfin[2 * g1 + 1] * gn1w[c1];
    const float sh1 = gn1b[c1] - sfin[2 * g1] * sc1;

    for (int it = 0; it < 64; ++it) {
        const size_t p = pbase + it * 2;
        const float4 f = feat[p + pt];
        const float y = b1c + w1r.x * f.x + w1r.y * f.y + w1r.z * f.z + w1r.w * f.w;
        const float h = fmaxf(0.f, fmaf(y, sc1, sh1));
        h_lds[(wv * 128 + it * 2 + pt) * 40 + c1] = f2bf(h);
    }

    s8v afr[4];
#pragma unroll
    for (int T = 0; T < 4; ++T) {
        const int row = T * 16 + col;
#pragma unroll
        for (int j2 = 0; j2 < 8; ++j2)
            afr[T][j2] = (short)f2bf(w2[row * 32 + quad * 8 + j2]);
    }

    float b2v[4][4], sc2v[4][4], sh2v[4][4];
#pragma unroll
    for (int T = 0; T < 4; ++T)
#pragma unroll
        for (int r4 = 0; r4 < 4; ++r4) {
            const int cch = T * 16 + quad * 4 + r4;
            b2v[T][r4] = b2[cch];
            if (MODE == 1) {
                const int g2 = cch >> 3;
                const float sc = sfin[8 + 2 * g2 + 1] * gn2w[cch];
                sc2v[T][r4] = sc;
                sh2v[T][r4] = gn2b[cch] - sfin[8 + 2 * g2] * sc + b2[cch] * sc;
            }
        }

    float gsum[4] = {0, 0, 0, 0}, gsq[4] = {0, 0, 0, 0};

    for (int pt16 = 0; pt16 < 8; ++pt16) {
        const int row = wv * 128 + pt16 * 16 + col;
        const s8v bfr = *(const s8v*)&h_lds[row * 40 + quad * 8];
        f32x4 acc[4];
#pragma unroll
        for (int T = 0; T < 4; ++T) {
            acc[T] = (f32x4){0.f, 0.f, 0.f, 0.f};
            acc[T] = __builtin_amdgcn_mfma_f32_16x16x32_bf16(afr[T], bfr, acc[T], 0, 0, 0);
        }
        if (MODE == 0) {
#pragma unroll
            for (int T = 0; T < 4; ++T)
#pragma unroll
                for (int r4 = 0; r4 < 4; ++r4) {
                    const float v = acc[T][r4] + b2v[T][r4];
                    gsum[T] += v;
                    gsq[T] = fmaf(v, v, gsq[T]);
                }
        } else {
            float s = -3.0e38f;
#pragma unroll
            for (int T = 0; T < 4; ++T)
#pragma unroll
                for (int r4 = 0; r4 < 4; ++r4)
                    s = fmaxf(s, fmaxf(0.f, fmaf(acc[T][r4], sc2v[T][r4], sh2v[T][r4])));
            s = fmaxf(s, __shfl_xor(s, 16));
            s = fmaxf(s, __shfl_xor(s, 32));
            if (quad == 0) ssc[wv * 128 + pt16 * 16 + col] = s;
        }
    }

    if (MODE == 0) {
#pragma unroll
        for (int T = 0; T < 4; ++T) {
#pragma unroll
            for (int o = 1; o < 16; o <<= 1) {
                gsum[T] += __shfl_xor(gsum[T], o);
                gsq[T] += __shfl_xor(gsq[T], o);
            }
            gsum[T] += __shfl_xor(gsum[T], 16);
            gsq[T] += __shfl_xor(gsq[T], 16);
        }
        if (lane == 0) {
#pragma unroll
            for (int T = 0; T < 4; ++T) {
                atomicAdd(&sacc[2 * T], gsum[T]);
                atomicAdd(&sacc[8 + 2 * T], gsq[T]);
            }
        }
        if (lane == 32) {
#pragma unroll
            for (int T = 0; T < 4; ++T) {
                atomicAdd(&sacc[2 * T + 1], gsum[T]);
                atomicAdd(&sacc[8 + 2 * T + 1], gsq[T]);
            }
        }
        __syncthreads();
        if (t < 16) atomicAdd(&stats2[b * 16 + t], sacc[t]);
    } else {
        __syncthreads();
        const int qi = t >> 4, sub = t & 15;
        const int qg = (b * N * 32 + pblock) / 32 + qi;
        const int n = qg - b * N;
        const float s0 = ssc[qi * 32 + sub], s1 = ssc[qi * 32 + 16 + sub];
        float mx = fmaxf(s0, s1);
#pragma unroll
        for (int o = 8; o; o >>= 1) mx = fmaxf(mx, __shfl_xor(mx, o));
        const float e0 = __expf(s0 - mx), e1 = __expf(s1 - mx);
        float ssum = e0 + e1;
#pragma unroll
        for (int o = 8; o; o >>= 1) ssum += __shfl_xor(ssum, o);
        const float4 qc = newp[qg];
        const float4 f0 = feat[(size_t)qg * 32 + sub];
        const float4 f1 = feat[(size_t)qg * 32 + 16 + sub];
        float ax = e0 * (qc.x + f0.x) + e1 * (qc.x + f1.x);
        float ay = e0 * (qc.y + f0.y) + e1 * (qc.y + f1.y);
        float az = e0 * (qc.z + f0.z) + e1 * (qc.z + f1.z);
#pragma unroll
        for (int o = 8; o; o >>= 1) {
            ax += __shfl_xor(ax, o);
            ay += __shfl_xor(ay, o);
            az += __shfl_xor(az, o);
        }
        if (sub == 0) {
            const float inv = 1.f / ssum;
            out[(b * 3 + 0) * N + n] = ax * inv;
            out[(b * 3 + 1) * N + n] = ay * inv;
            out[(b * 3 + 2) * N + n] = az * inv;
        }
    }
}

// ---------------------------------------------------------------------------
extern "C" void kernel_launch(void* const* d_in, const int* in_sizes, int n_in,
                              void* d_out, int out_size, void* d_ws, size_t ws_size,
                              hipStream_t stream)
{
    const float* p0   = (const float*)d_in[0];
    const float* p1   = (const float*)d_in[1];
    const float* wt   = (const float*)d_in[3];
    const int*   perm = (const int*)d_in[4];
    const float* w1   = (const float*)d_in[5];
    const float* b1   = (const float*)d_in[6];
    const float* gn1w = (const float*)d_in[7];
    const float* gn1b = (const float*)d_in[8];
    const float* w2   = (const float*)d_in[9];
    const float* b2   = (const float*)d_in[10];
    const float* gn2w = (const float*)d_in[11];
    const float* gn2b = (const float*)d_in[12];
    float* out = (float*)d_out;

    const int B = in_sizes[3] / 2;
    const int N = in_sizes[0] / (3 * B);

    // workspace layout
    char* ws = (char*)d_ws;
    float4* spts = (float4*)ws;               // B*2*4096 float4 (z-sorted lists)
    size_t off = (size_t)B * 2 * 4096 * sizeof(float4);
    float4* feat = (float4*)(ws + off);       off += (size_t)B * N * 32 * sizeof(float4);
    float4* newp = (float4*)(ws + off);       off += (size_t)B * N * sizeof(float4);
    float* stats1 = (float*)(ws + off);       // B*14 moments (S[4], M[10])
    float* stats2 = stats1 + B * 14;          // B*16 (8 sums + 8 sumsqs)

    hipMemsetAsync(stats1, 0, (size_t)B * 30 * sizeof(float), stream);

    const float inv_cnt = 1.f / (8.f * (float)N * 32.f);

    zsort_kernel<<<B * 2, 1024, 0, stream>>>(p0, p1, spts, N);

    knn_kernel<<<(B * 2 * N) / (4 * TPW), 256, 0, stream>>>(
        p0, p1, wt, perm, spts, feat, newp, N);

    moment_stats_kernel<<<B * 64, 256, 0, stream>>>(feat, stats1, N);

    conv2_pass_kernel<0><<<(B * N * 32) / 512, 256, 0, stream>>>(
        feat, w1, b1, gn1w, gn1b, stats1, w2, b2, gn2w, gn2b, stats2,
        newp, out, N, inv_cnt);

    conv2_pass_kernel<1><<<(B * N * 32) / 512, 256, 0, stream>>>(
        feat, w1, b1, gn1w, gn1b, stats1, w2, b2, gn2w, gn2b, stats2,
        newp, out, N, inv_cnt);
}

// Round 9
// 445.738 us; speedup vs baseline: 1.2713x; 1.2713x over previous
//
#include <hip/hip_runtime.h>
#include <math.h>

#define RQ 6              // per-lane queue depth
constexpr int TPW = 8;    // (query,list) tasks per wave in knn
constexpr int WIN = 768;  // phase-1 window (12 chunks of 64)

typedef __attribute__((ext_vector_type(8))) short s8v;    // 8 bf16 (4 VGPRs)
typedef __attribute__((ext_vector_type(4))) float f32x4;  // MFMA acc

__device__ inline unsigned short f2bf(float x) {          // RNE f32->bf16
    const unsigned int u = __float_as_uint(x);
    return (unsigned short)((u + 0x7FFFu + ((u >> 16) & 1u)) >> 16);
}

// ---------------------------------------------------------------------------
// K0a: per-(b,list) 2048-tile bitonic sort of (zkey<<32|idx). Even tile
// written ascending, odd tile written reversed (descending) so the pair forms
// a bitonic 4096 sequence for the merge pass.
// ---------------------------------------------------------------------------
__global__ __launch_bounds__(1024) void zsort_tile_kernel(
    const float* __restrict__ p0, const float* __restrict__ p1,
    unsigned long long* __restrict__ tmp, int N)
{
    __shared__ unsigned long long arr[2048];
    const int t = threadIdx.x;
    const int tile = blockIdx.x, bl = tile >> 1, half = tile & 1;
    const int b = bl >> 1, list = bl & 1;
    const float* rb = (list ? p1 : p0) + (size_t)(b * 3) * N;
    const int base = half * 2048;
    for (int i = t; i < 2048; i += 1024) {
        const unsigned int u = __float_as_uint(rb[2 * N + base + i]);
        const unsigned int key = u ^ ((u >> 31) ? 0xFFFFFFFFu : 0x80000000u);
        arr[i] = ((unsigned long long)key << 32) | (unsigned int)(base + i);
    }
    __syncthreads();
    for (int k = 2; k <= 2048; k <<= 1)
        for (int jj = k >> 1; jj; jj >>= 1) {
            for (int i = t; i < 2048; i += 1024) {
                const int ixj = i ^ jj;
                if (ixj > i) {
                    const unsigned long long a = arr[i], c = arr[ixj];
                    if ((a > c) == ((i & k) == 0)) { arr[i] = c; arr[ixj] = a; }
                }
            }
            __syncthreads();
        }
    // even half ascending; odd half reversed -> descending
    for (int i = t; i < 2048; i += 1024) {
        const int o = half ? (2047 - i) : i;
        tmp[(size_t)bl * 4096 + base + o] = arr[i];
    }
}

// ---------------------------------------------------------------------------
// K0b: global bitonic pass k=4096, j=2048 (cross-half compare).
// ---------------------------------------------------------------------------
__global__ __launch_bounds__(1024) void zsort_merge_kernel(
    unsigned long long* __restrict__ tmp)
{
    const int bl = blockIdx.x >> 1;
    const int i = (blockIdx.x & 1) * 1024 + threadIdx.x;   // 0..2047
    unsigned long long* a = tmp + (size_t)bl * 4096;
    const unsigned long long x = a[i], y = a[i + 2048];
    a[i] = x < y ? x : y;
    a[i + 2048] = x < y ? y : x;
}

// ---------------------------------------------------------------------------
// K0c: local bitonic merge j=1024..1 per 2048-half, then gather coords ->
// sp[] = float4(x,y,z,|p|^2) in ascending-z order.
// ---------------------------------------------------------------------------
__global__ __launch_bounds__(1024) void zsort_final_kernel(
    const float* __restrict__ p0, const float* __restrict__ p1,
    const unsigned long long* __restrict__ tmp,
    float4* __restrict__ sp, int N)
{
    __shared__ unsigned long long arr[2048];
    const int t = threadIdx.x;
    const int tile = blockIdx.x, bl = tile >> 1, half = tile & 1;
    const int b = bl >> 1, list = bl & 1;
    const float* rb = (list ? p1 : p0) + (size_t)(b * 3) * N;
    const int base = half * 2048;
    for (int i = t; i < 2048; i += 1024) arr[i] = tmp[(size_t)bl * 4096 + base + i];
    __syncthreads();
    for (int jj = 1024; jj; jj >>= 1) {
        for (int i = t; i < 2048; i += 1024) {
            const int ixj = i ^ jj;
            if (ixj > i) {
                const unsigned long long a = arr[i], c = arr[ixj];
                if (a > c) { arr[i] = c; arr[ixj] = a; }
            }
        }
        __syncthreads();
    }
    for (int i = t; i < 2048; i += 1024) {
        const int oi = (int)(arr[i] & 0xFFFFFFFFu);
        const float x = rb[oi], y = rb[N + oi], z = rb[2 * N + oi];
        sp[(size_t)bl * 4096 + base + i] =
            make_float4(x, y, z, fmaf(x, x, fmaf(y, y, z * z)));
    }
}

// ---------------------------------------------------------------------------
// K1: exact kNN, two-phase z-window. Wave per (query,list) task, no LDS.
// Phase 1: scan the WIN z-nearest candidates (fixed 12 chunks, unrolled).
// T = exact kk-th smallest key of phase-1 set (pop-rounds on a queue COPY) --
// a valid upper bound on the final kk-th. Phase 2: expand outward only while
// the frontier's dz^2*(1-eps) <= T (z-sorted => all farther entries have
// larger dz^2) -- EXACT. Queue/extraction identical to verified round-6.
// ---------------------------------------------------------------------------
__global__ __launch_bounds__(256, 8) void knn_kernel(
    const float* __restrict__ p0, const float* __restrict__ p1,
    const float* __restrict__ wt, const int* __restrict__ perm,
    const float4* __restrict__ sp,
    float4* __restrict__ feat, float4* __restrict__ newp, int N)
{
    const int lane = threadIdx.x & 63;
    const int gwave = (int)((blockIdx.x * 256 + threadIdx.x) >> 6);

    for (int ti = 0; ti < TPW; ++ti) {
        const int task = gwave * TPW + ti;
        const int b = task / (2 * N);
        const int rem = task - b * 2 * N;
        const int list = rem / N;
        const int n = rem - list * N;
        const int q = b * N + n;

        const float wt0 = wt[b * 2];
        const int N0 = (int)(N * wt0);
        const int k0 = (int)(32 * wt0);
        const int kk = list ? (32 - k0) : k0;     // in [8,24]

        int j; const float* src;
        if (n < N0) { j = perm[(b * 2) * N + n];            src = p0; }
        else        { j = perm[(b * 2 + 1) * N + (n - N0)]; src = p1; }
        const float qx = __uint_as_float(__builtin_amdgcn_readfirstlane(
                             __float_as_uint(src[(b * 3) * N + j])));
        const float qy = __uint_as_float(__builtin_amdgcn_readfirstlane(
                             __float_as_uint(src[(b * 3 + 1) * N + j])));
        const float qz = __uint_as_float(__builtin_amdgcn_readfirstlane(
                             __float_as_uint(src[(b * 3 + 2) * N + j])));
        const float qq = qx * qx + qy * qy + qz * qz;

        const float4* L = sp + (size_t)(b * 2 + list) * 4096;

        // two-level 64-way probe: c = insertion rank of qz in sorted z
        const float zs = L[lane << 6].z;
        const int cnt1 = __popcll(__ballot(zs <= qz));
        const int base1 = (cnt1 > 0 ? cnt1 - 1 : 0) << 6;
        const float z2 = L[base1 + lane].z;
        const int cnt2 = __popcll(__ballot(z2 <= qz));
        const int c = base1 + cnt2;

        int base0 = c - WIN / 2;
        base0 = base0 < 0 ? 0 : (base0 > 4096 - WIN ? 4096 - WIN : base0);

        unsigned int kh[RQ], kl[RQ];
#pragma unroll
        for (int s = 0; s < RQ; ++s) { kh[s] = 0xFFFFFFFFu; kl[s] = 0xFFFFFFFFu; }

        // ---- phase 1: WIN/64 chunks, all in-bounds ----
#pragma unroll
        for (int ch = 0; ch < WIN / 64; ++ch) {
            const int pos = base0 + (ch << 6) + lane;
            const float4 pc = L[pos];
            const float dt = fmaf(qz, pc.z, fmaf(qy, pc.y, qx * pc.x));
            const float d = fmaxf(fmaf(-2.f, dt, pc.w + qq), 0.f);
            const unsigned int key = __float_as_uint(d);
            bool cb[RQ];
#pragma unroll
            for (int s = 0; s < RQ; ++s) cb[s] = key < kh[s];
#pragma unroll
            for (int s = RQ - 1; s >= 1; --s) {
                kh[s] = cb[s - 1] ? kh[s - 1] : (cb[s] ? key : kh[s]);
                kl[s] = cb[s - 1] ? kl[s - 1] : (cb[s] ? (unsigned int)pos : kl[s]);
            }
            kh[0] = cb[0] ? key : kh[0];
            kl[0] = cb[0] ? (unsigned int)pos : kl[0];
        }

        // ---- T = kk-th smallest of phase-1 set (on a copy; pop-all-tied
        //      gives g_kk >= exact kk-th -> valid upper bound) ----
        unsigned int tk[RQ];
#pragma unroll
        for (int s = 0; s < RQ; ++s) tk[s] = kh[s];
        unsigned int g = 0;
        for (int rr = 0; rr < kk; ++rr) {
            g = tk[0];
#pragma unroll
            for (int off = 32; off; off >>= 1) g = min(g, __shfl_xor(g, off));
            const bool w = (tk[0] == g);
#pragma unroll
            for (int s = 0; s < RQ - 1; ++s) tk[s] = w ? tk[s + 1] : tk[s];
            tk[RQ - 1] = w ? 0xFFFFFFFFu : tk[RQ - 1];
        }
        const float T_f = __uint_as_float(__builtin_amdgcn_readfirstlane(g));

        // ---- phase 2: expand outward while frontier dz^2 can beat T ----
        int lft = base0 - 1, r = base0 + WIN;
        const float zl0 = L[base0].z, zr0 = L[base0 + WIN - 1].z;
        float dzL2 = (qz - zl0) * (qz - zl0) * 0.99999f;
        float dzR2 = (zr0 - qz) * (zr0 - qz) * 0.99999f;
        bool aliveL = (lft >= 0) && !(dzL2 > T_f);
        bool aliveR = (r <= 4095) && !(dzR2 > T_f);

        while (aliveL || aliveR) {
            const bool doR = aliveR && (!aliveL || dzR2 <= dzL2);
            const int base = doR ? r : (lft - 63);
            const int pos = base + lane;
            const bool valid = ((unsigned)pos < 4096u);
            const float4 pc = L[valid ? pos : 0];
            const float dt = fmaf(qz, pc.z, fmaf(qy, pc.y, qx * pc.x));
            const float d = fmaxf(fmaf(-2.f, dt, pc.w + qq), 0.f);
            const unsigned int key = valid ? __float_as_uint(d) : 0xFFFFFFFFu;
            bool cb[RQ];
#pragma unroll
            for (int s = 0; s < RQ; ++s) cb[s] = key < kh[s];
#pragma unroll
            for (int s = RQ - 1; s >= 1; --s) {
                kh[s] = cb[s - 1] ? kh[s - 1] : (cb[s] ? key : kh[s]);
                kl[s] = cb[s - 1] ? kl[s - 1] : (cb[s] ? (unsigned int)pos : kl[s]);
            }
            kh[0] = cb[0] ? key : kh[0];
            kl[0] = cb[0] ? (unsigned int)pos : kl[0];

            if (doR) {
                const float pz = __shfl(pc.z, 63);
                r = base + 64;
                dzR2 = (pz - qz) * (pz - qz) * 0.99999f;
                aliveR = (r <= 4095) && !(dzR2 > T_f);
            } else {
                const float pz = __shfl(pc.z, 0);
                lft = base - 1;
                dzL2 = (qz - pz) * (qz - pz) * 0.99999f;
                aliveL = (lft >= 0) && !(dzL2 > T_f);
            }
        }

        // ---- extraction: kk rounds of key wave-min + smallest-idx tiebreak ----
        unsigned int mwin = 0;
        for (int rr = 0; rr < kk; ++rr) {
            unsigned int gg = kh[0];
#pragma unroll
            for (int off = 32; off; off >>= 1) gg = min(gg, __shfl_xor(gg, off));
            const bool tied = (kh[0] == gg);
            unsigned int mc;
            const unsigned long long bal = __ballot(tied);
            if (bal & (bal - 1)) {
                mc = tied ? kl[0] : 0xFFFFFFFFu;
#pragma unroll
                for (int off = 32; off; off >>= 1) mc = min(mc, __shfl_xor(mc, off));
            } else {
                mc = __shfl(kl[0], (int)__ffsll((long long)bal) - 1);
            }
            const bool w = tied && (kl[0] == mc);
            if (lane == rr) mwin = mc;
#pragma unroll
            for (int s = 0; s < RQ - 1; ++s) {
                kh[s] = w ? kh[s + 1] : kh[s];
                kl[s] = w ? kl[s + 1] : kl[s];
            }
            kh[RQ - 1] = w ? 0xFFFFFFFFu : kh[RQ - 1];
            kl[RQ - 1] = w ? 0xFFFFFFFFu : kl[RQ - 1];
        }
        const int obase = (q << 5) + (list ? k0 : 0);
        if (lane < kk) {
            const float4 pc = L[mwin];
            const float rx = pc.x - qx, ry = pc.y - qy, rz = pc.z - qz;
            feat[obase + lane] =
                make_float4(rx, ry, rz,
                            sqrtf(fmaf(rx, rx, fmaf(ry, ry, rz * rz))));
        }
        if (list == 0 && lane == 0) newp[q] = make_float4(qx, qy, qz, 0.f);
    }
}

// ---------------------------------------------------------------------------
// K2: per-sample feature moments (S=sum f [4], M=sum f f^T [10]).
// ---------------------------------------------------------------------------
__global__ __launch_bounds__(256) void moment_stats_kernel(
    const float4* __restrict__ feat, float* __restrict__ stats1, int N)
{
    const int t = threadIdx.x, lane = t & 63;
    const int bpb = 64;
    const int b = blockIdx.x / bpb;
    const int ppb = (N * 32) / bpb;
    const size_t base = (size_t)b * N * 32 + (size_t)(blockIdx.x % bpb) * ppb;
    float a[14];
#pragma unroll
    for (int i = 0; i < 14; ++i) a[i] = 0.f;
    for (int i = t; i < ppb; i += 256) {
        const float4 f = feat[base + i];
        a[0] += f.x; a[1] += f.y; a[2] += f.z; a[3] += f.w;
        a[4] = fmaf(f.x, f.x, a[4]);  a[5] = fmaf(f.x, f.y, a[5]);
        a[6] = fmaf(f.x, f.z, a[6]);  a[7] = fmaf(f.x, f.w, a[7]);
        a[8] = fmaf(f.y, f.y, a[8]);  a[9] = fmaf(f.y, f.z, a[9]);
        a[10] = fmaf(f.y, f.w, a[10]); a[11] = fmaf(f.z, f.z, a[11]);
        a[12] = fmaf(f.z, f.w, a[12]); a[13] = fmaf(f.w, f.w, a[13]);
    }
#pragma unroll
    for (int i = 0; i < 14; ++i) {
        float x = a[i];
#pragma unroll
        for (int o = 32; o; o >>= 1) x += __shfl_down(x, o);
        a[i] = x;
    }
    __shared__ float sm[14];
    if (t < 14) sm[t] = 0.f;
    __syncthreads();
    if (lane == 0) {
#pragma unroll
        for (int i = 0; i < 14; ++i) atomicAdd(&sm[i], a[i]);
    }
    __syncthreads();
    if (t < 14) atomicAdd(&stats1[b * 14 + t], sm[t]);
}

// ---------------------------------------------------------------------------
// K3/K4: conv1+gn1+relu -> bf16 h in LDS -> conv2 via MFMA 16x16x32
// (unchanged from round 7).
// ---------------------------------------------------------------------------
template <int MODE>
__global__ __launch_bounds__(256) void conv2_pass_kernel(
    const float4* __restrict__ feat,
    const float* __restrict__ w1, const float* __restrict__ b1,
    const float* __restrict__ gn1w, const float* __restrict__ gn1b,
    const float* __restrict__ stats1,
    const float* __restrict__ w2, const float* __restrict__ b2,
    const float* __restrict__ gn2w, const float* __restrict__ gn2b,
    float* __restrict__ stats2,
    const float4* __restrict__ newp, float* __restrict__ out,
    int N, float inv_cnt)
{
    const int t = threadIdx.x, lane = t & 63, wv = t >> 6;
    const int quad = lane >> 4, col = lane & 15;
    const int bpb = (N * 32) / 512;
    const int b = blockIdx.x / bpb;
    const int pblock = (blockIdx.x - b * bpb) * 512;
    const size_t pbase = (size_t)b * N * 32 + pblock + wv * 128;

    __shared__ float sfin[24];
    __shared__ float sacc[16];
    __shared__ unsigned short h_lds[512 * 40];
    __shared__ float ssc[512];

    if (t < 16) sacc[t] = 0.f;
    if (t < 4) {
        const float cnt = (float)(N * 32);
        const float* mm = stats1 + b * 14;
        const float S0 = mm[0], S1 = mm[1], S2 = mm[2], S3 = mm[3];
        float sum = 0.f, sq = 0.f;
        for (int cch = 0; cch < 8; ++cch) {
            const int cid = t * 8 + cch;
            const float4 w = ((const float4*)w1)[cid];
            const float bb = b1[cid];
            const float ws = w.x * S0 + w.y * S1 + w.z * S2 + w.w * S3;
            const float wMw =
                w.x * w.x * mm[4] + w.y * w.y * mm[8] + w.z * w.z * mm[11] +
                w.w * w.w * mm[13] +
                2.f * (w.x * w.y * mm[5] + w.x * w.z * mm[6] + w.x * w.w * mm[7] +
                       w.y * w.z * mm[9] + w.y * w.w * mm[10] + w.z * w.w * mm[12]);
            sum += cnt * bb + ws;
            sq += cnt * bb * bb + 2.f * bb * ws + wMw;
        }
        const float mu = sum * inv_cnt, var = sq * inv_cnt - mu * mu;
        sfin[2 * t] = mu; sfin[2 * t + 1] = rsqrtf(var + 1e-5f);
    }
    if (MODE == 1 && t >= 4 && t < 12) {
        const int g = t - 4;
        const float S = stats2[b * 16 + g], Q = stats2[b * 16 + 8 + g];
        const float mu = S * inv_cnt, var = Q * inv_cnt - mu * mu;
        sfin[8 + 2 * g] = mu; sfin[8 + 2 * g + 1] = rsqrtf(var + 1e-5f);
    }
    __syncthreads();

    const int c1 = lane & 31, pt = lane >> 5;
    const float4 w1r = ((const float4*)w1)[c1];
    const float b1c = b1[c1];
    const int g1 = c1 >> 3;
    const float sc1 = sfin[2 * g1 + 1] * gn1w[c1];
    const float sh1 = gn1b[c1] - sfin[2 * g1] * sc1;

    for (int it = 0; it < 64; ++it) {
        const size_t p = pbase + it * 2;
        const float4 f = feat[p + pt];
        const float y = b1c + w1r.x * f.x + w1r.y * f.y + w1r.z * f.z + w1r.w * f.w;
        const float h = fmaxf(0.f, fmaf(y, sc1, sh1));
        h_lds[(wv * 128 + it * 2 + pt) * 40 + c1] = f2bf(h);
    }

    s8v afr[4];
#pragma unroll
    for (int T = 0; T < 4; ++T) {
        const int row = T * 16 + col;
#pragma unroll
        for (int j2 = 0; j2 < 8; ++j2)
            afr[T][j2] = (short)f2bf(w2[row * 32 + quad * 8 + j2]);
    }

    float b2v[4][4], sc2v[4][4], sh2v[4][4];
#pragma unroll
    for (int T = 0; T < 4; ++T)
#pragma unroll
        for (int r4 = 0; r4 < 4; ++r4) {
            const int cch = T * 16 + quad * 4 + r4;
            b2v[T][r4] = b2[cch];
            if (MODE == 1) {
                const int g2 = cch >> 3;
                const float sc = sfin[8 + 2 * g2 + 1] * gn2w[cch];
                sc2v[T][r4] = sc;
                sh2v[T][r4] = gn2b[cch] - sfin[8 + 2 * g2] * sc + b2[cch] * sc;
            }
        }

    float gsum[4] = {0, 0, 0, 0}, gsq[4] = {0, 0, 0, 0};

    for (int pt16 = 0; pt16 < 8; ++pt16) {
        const int row = wv * 128 + pt16 * 16 + col;
        const s8v bfr = *(const s8v*)&h_lds[row * 40 + quad * 8];
        f32x4 acc[4];
#pragma unroll
        for (int T = 0; T < 4; ++T) {
            acc[T] = (f32x4){0.f, 0.f, 0.f, 0.f};
            acc[T] = __builtin_amdgcn_mfma_f32_16x16x32_bf16(afr[T], bfr, acc[T], 0, 0, 0);
        }
        if (MODE == 0) {
#pragma unroll
            for (int T = 0; T < 4; ++T)
#pragma unroll
                for (int r4 = 0; r4 < 4; ++r4) {
                    const float v = acc[T][r4] + b2v[T][r4];
                    gsum[T] += v;
                    gsq[T] = fmaf(v, v, gsq[T]);
                }
        } else {
            float s = -3.0e38f;
#pragma unroll
            for (int T = 0; T < 4; ++T)
#pragma unroll
                for (int r4 = 0; r4 < 4; ++r4)
                    s = fmaxf(s, fmaxf(0.f, fmaf(acc[T][r4], sc2v[T][r4], sh2v[T][r4])));
            s = fmaxf(s, __shfl_xor(s, 16));
            s = fmaxf(s, __shfl_xor(s, 32));
            if (quad == 0) ssc[wv * 128 + pt16 * 16 + col] = s;
        }
    }

    if (MODE == 0) {
#pragma unroll
        for (int T = 0; T < 4; ++T) {
#pragma unroll
            for (int o = 1; o < 16; o <<= 1) {
                gsum[T] += __shfl_xor(gsum[T], o);
                gsq[T] += __shfl_xor(gsq[T], o);
            }
            gsum[T] += __shfl_xor(gsum[T], 16);
            gsq[T] += __shfl_xor(gsq[T], 16);
        }
        if (lane == 0) {
#pragma unroll
            for (int T = 0; T < 4; ++T) {
                atomicAdd(&sacc[2 * T], gsum[T]);
                atomicAdd(&sacc[8 + 2 * T], gsq[T]);
            }
        }
        if (lane == 32) {
#pragma unroll
            for (int T = 0; T < 4; ++T) {
                atomicAdd(&sacc[2 * T + 1], gsum[T]);
                atomicAdd(&sacc[8 + 2 * T + 1], gsq[T]);
            }
        }
        __syncthreads();
        if (t < 16) atomicAdd(&stats2[b * 16 + t], sacc[t]);
    } else {
        __syncthreads();
        const int qi = t >> 4, sub = t & 15;
        const int qg = (b * N * 32 + pblock) / 32 + qi;
        const int n = qg - b * N;
        const float s0 = ssc[qi * 32 + sub], s1 = ssc[qi * 32 + 16 + sub];
        float mx = fmaxf(s0, s1);
#pragma unroll
        for (int o = 8; o; o >>= 1) mx = fmaxf(mx, __shfl_xor(mx, o));
        const float e0 = __expf(s0 - mx), e1 = __expf(s1 - mx);
        float ssum = e0 + e1;
#pragma unroll
        for (int o = 8; o; o >>= 1) ssum += __shfl_xor(ssum, o);
        const float4 qc = newp[qg];
        const float4 f0 = feat[(size_t)qg * 32 + sub];
        const float4 f1 = feat[(size_t)qg * 32 + 16 + sub];
        float ax = e0 * (qc.x + f0.x) + e1 * (qc.x + f1.x);
        float ay = e0 * (qc.y + f0.y) + e1 * (qc.y + f1.y);
        float az = e0 * (qc.z + f0.z) + e1 * (qc.z + f1.z);
#pragma unroll
        for (int o = 8; o; o >>= 1) {
            ax += __shfl_xor(ax, o);
            ay += __shfl_xor(ay, o);
            az += __shfl_xor(az, o);
        }
        if (sub == 0) {
            const float inv = 1.f / ssum;
            out[(b * 3 + 0) * N + n] = ax * inv;
            out[(b * 3 + 1) * N + n] = ay * inv;
            out[(b * 3 + 2) * N + n] = az * inv;
        }
    }
}

// ---------------------------------------------------------------------------
extern "C" void kernel_launch(void* const* d_in, const int* in_sizes, int n_in,
                              void* d_out, int out_size, void* d_ws, size_t ws_size,
                              hipStream_t stream)
{
    const float* p0   = (const float*)d_in[0];
    const float* p1   = (const float*)d_in[1];
    const float* wt   = (const float*)d_in[3];
    const int*   perm = (const int*)d_in[4];
    const float* w1   = (const float*)d_in[5];
    const float* b1   = (const float*)d_in[6];
    const float* gn1w = (const float*)d_in[7];
    const float* gn1b = (const float*)d_in[8];
    const float* w2   = (const float*)d_in[9];
    const float* b2   = (const float*)d_in[10];
    const float* gn2w = (const float*)d_in[11];
    const float* gn2b = (const float*)d_in[12];
    float* out = (float*)d_out;

    const int B = in_sizes[3] / 2;
    const int N = in_sizes[0] / (3 * B);

    // workspace layout
    char* ws = (char*)d_ws;
    float4* spts = (float4*)ws;               // B*2*4096 float4 (z-sorted lists)
    size_t off = (size_t)B * 2 * 4096 * sizeof(float4);
    unsigned long long* ztmp = (unsigned long long*)(ws + off);
    off += (size_t)B * 2 * 4096 * sizeof(unsigned long long);
    float4* feat = (float4*)(ws + off);       off += (size_t)B * N * 32 * sizeof(float4);
    float4* newp = (float4*)(ws + off);       off += (size_t)B * N * sizeof(float4);
    float* stats1 = (float*)(ws + off);       // B*14 moments (S[4], M[10])
    float* stats2 = stats1 + B * 14;          // B*16 (8 sums + 8 sumsqs)

    hipMemsetAsync(stats1, 0, (size_t)B * 30 * sizeof(float), stream);

    const float inv_cnt = 1.f / (8.f * (float)N * 32.f);

    zsort_tile_kernel<<<B * 2 * 2, 1024, 0, stream>>>(p0, p1, ztmp, N);
    zsort_merge_kernel<<<B * 2 * 2, 1024, 0, stream>>>(ztmp);
    zsort_final_kernel<<<B * 2 * 2, 1024, 0, stream>>>(p0, p1, ztmp, spts, N);

    knn_kernel<<<(B * 2 * N) / (4 * TPW), 256, 0, stream>>>(
        p0, p1, wt, perm, spts, feat, newp, N);

    moment_stats_kernel<<<B * 64, 256, 0, stream>>>(feat, stats1, N);

    conv2_pass_kernel<0><<<(B * N * 32) / 512, 256, 0, stream>>>(
        feat, w1, b1, gn1w, gn1b, stats1, w2, b2, gn2w, gn2b, stats2,
        newp, out, N, inv_cnt);

    conv2_pass_kernel<1><<<(B * N * 32) / 512, 256, 0, stream>>>(
        feat, w1, b1, gn1w, gn1b, stats1, w2, b2, gn2w, gn2b, stats2,
        newp, out, N, inv_cnt);
}

// Round 10
// 427.980 us; speedup vs baseline: 1.3240x; 1.0415x over previous
//
#include <hip/hip_runtime.h>
#include <math.h>

#define RQ 6              // per-lane queue depth
constexpr int TPW = 8;    // (query,list) tasks per wave in knn
constexpr int PBINS = 12; // phase-1 window in bins (~768 ranks)

typedef __attribute__((ext_vector_type(8))) short s8v;    // 8 bf16 (4 VGPRs)
typedef __attribute__((ext_vector_type(4))) float f32x4;  // MFMA acc

__device__ inline unsigned short f2bf(float x) {          // RNE f32->bf16
    const unsigned int u = __float_as_uint(x);
    return (unsigned short)((u + 0x7FFFu + ((u >> 16) & 1u)) >> 16);
}

// N(0,1) quantiles at i/64, i=1..63. Bin i spans [ZB[i-1], ZB[i]) with
// ZB[-1]=-inf, ZB[63]=+inf. PERF-ONLY hint (equal expected counts); CSR uses
// exact counts so correctness is distribution-independent.
__constant__ float ZB[63] = {
    -2.1539f, -1.8627f, -1.6759f, -1.5341f, -1.4178f, -1.3180f, -1.2299f, -1.1503f,
    -1.0775f, -1.0100f, -0.9468f, -0.8871f, -0.8305f, -0.7764f, -0.7245f, -0.6745f,
    -0.6261f, -0.5791f, -0.5334f, -0.4888f, -0.4451f, -0.4023f, -0.3601f, -0.3186f,
    -0.2776f, -0.2372f, -0.1971f, -0.1573f, -0.1178f, -0.0784f, -0.0392f,  0.0000f,
     0.0392f,  0.0784f,  0.1178f,  0.1573f,  0.1971f,  0.2372f,  0.2776f,  0.3186f,
     0.3601f,  0.4023f,  0.4451f,  0.4888f,  0.5334f,  0.5791f,  0.6261f,  0.6745f,
     0.7245f,  0.7764f,  0.8305f,  0.8871f,  0.9468f,  1.0100f,  1.0775f,  1.1503f,
     1.2299f,  1.3180f,  1.4178f,  1.5341f,  1.6759f,  1.8627f,  2.1539f };

// ---------------------------------------------------------------------------
// K0: z-bin CSR build. One block per (b,list): count -> prefix -> scatter.
// sp[] = float4(x,y,z,|p|^2) grouped by z-bin; starts[bl*65+i] = CSR offsets.
// ---------------------------------------------------------------------------
__global__ __launch_bounds__(1024) void zbin_kernel(
    const float* __restrict__ p0, const float* __restrict__ p1,
    float4* __restrict__ sp, int* __restrict__ starts, int N)
{
    __shared__ int cnt[64], off[64], cur[64];
    const int t = threadIdx.x;
    const int bl = blockIdx.x;                    // b*2 + list
    const int b = bl >> 1, list = bl & 1;
    const float* rb = (list ? p1 : p0) + (size_t)(b * 3) * N;
    if (t < 64) { cnt[t] = 0; cur[t] = 0; }
    __syncthreads();
    int mybin[4]; float mx[4], my[4], mz[4];
    for (int i = 0; i < 4; ++i) {
        const int idx = i * 1024 + t;
        const float z = rb[2 * N + idx];
        mx[i] = rb[idx]; my[i] = rb[N + idx]; mz[i] = z;
        int bin = 0;
#pragma unroll
        for (int s = 32; s; s >>= 1)
            if (bin + s <= 63 && z >= ZB[bin + s - 1]) bin += s;
        mybin[i] = bin;
        atomicAdd(&cnt[bin], 1);
    }
    __syncthreads();
    if (t < 64) {                                 // wave 0: exclusive prefix
        const int v = cnt[t];
        int x = v;
#pragma unroll
        for (int o = 1; o < 64; o <<= 1) {
            const int y = __shfl_up(x, o);
            if (t >= o) x += y;
        }
        off[t] = x - v;
        starts[bl * 65 + t] = x - v;
        if (t == 63) starts[bl * 65 + 64] = x;
    }
    __syncthreads();
    for (int i = 0; i < 4; ++i) {
        const int bin = mybin[i];
        const int pos = off[bin] + atomicAdd(&cur[bin], 1);
        sp[(size_t)bl * 4096 + pos] =
            make_float4(mx[i], my[i], mz[i],
                        fmaf(mx[i], mx[i], fmaf(my[i], my[i], mz[i] * mz[i])));
    }
}

// ---------------------------------------------------------------------------
// K1: exact kNN over z-bin CSR. Wave per (query,list) task, no LDS.
// Phase 1: contiguous CSR range of PBINS bins around the query's bin
// (prefetch-pipelined chunks of 64). T = m_(kk) of the 64 lane-mins via a
// 21-stage wave bitonic sort -- valid upper bound on the true kk-th (>=kk
// lanes have min <= m_(kk) => >=kk entries <= m_(kk)). Phase 2: expand bin
// by bin while (bin-edge dz)^2*(1-eps) <= T  (bin edges from ZB) -- EXACT.
// Queue/extraction identical to the verified round-6 kernel.
// ---------------------------------------------------------------------------
__global__ __launch_bounds__(256, 8) void knn_kernel(
    const float* __restrict__ p0, const float* __restrict__ p1,
    const float* __restrict__ wt, const int* __restrict__ perm,
    const float4* __restrict__ sp, const int* __restrict__ starts,
    float4* __restrict__ feat, float4* __restrict__ newp, int N)
{
    const int lane = threadIdx.x & 63;
    const int gwave = (int)((blockIdx.x * 256 + threadIdx.x) >> 6);

    for (int ti = 0; ti < TPW; ++ti) {
        const int task = gwave * TPW + ti;
        const int b = task / (2 * N);
        const int rem = task - b * 2 * N;
        const int list = rem / N;
        const int n = rem - list * N;
        const int q = b * N + n;
        const int bl = b * 2 + list;

        const float wt0 = wt[b * 2];
        const int N0 = (int)(N * wt0);
        const int k0 = (int)(32 * wt0);
        const int kk = list ? (32 - k0) : k0;     // in [8,24]

        int j; const float* src;
        if (n < N0) { j = perm[(b * 2) * N + n];            src = p0; }
        else        { j = perm[(b * 2 + 1) * N + (n - N0)]; src = p1; }
        const float qx = __uint_as_float(__builtin_amdgcn_readfirstlane(
                             __float_as_uint(src[(b * 3) * N + j])));
        const float qy = __uint_as_float(__builtin_amdgcn_readfirstlane(
                             __float_as_uint(src[(b * 3 + 1) * N + j])));
        const float qz = __uint_as_float(__builtin_amdgcn_readfirstlane(
                             __float_as_uint(src[(b * 3 + 2) * N + j])));
        const float qq = qx * qx + qy * qy + qz * qz;

        const float4* L = sp + (size_t)bl * 4096;

        // query bin via one ballot over the constant boundary table
        const float bv = (lane < 63) ? ZB[lane] : 3.0e38f;
        const int qbin = __popcll(__ballot(qz >= bv));    // 0..63
        int lo = qbin - PBINS / 2;
        lo = lo < 0 ? 0 : (lo > 64 - PBINS ? 64 - PBINS : lo);
        const int hi = lo + PBINS;
        const int s0 = starts[bl * 65 + lo];
        const int e0 = starts[bl * 65 + hi];

        unsigned int kh[RQ], kl[RQ];
#pragma unroll
        for (int s = 0; s < RQ; ++s) { kh[s] = 0xFFFFFFFFu; kl[s] = 0xFFFFFFFFu; }

        // ---- phase 1: contiguous [s0,e0), 2-deep prefetch pipeline ----
        const int nch = (e0 - s0 + 63) >> 6;
        float4 pcur;
        if (nch > 0) pcur = L[min(s0 + lane, e0 - 1)];
        for (int ch = 0; ch < nch; ++ch) {
            float4 pnxt = pcur;
            if (ch + 1 < nch)
                pnxt = L[min(s0 + ((ch + 1) << 6) + lane, e0 - 1)];
            const int pos = s0 + (ch << 6) + lane;
            const bool valid = pos < e0;
            const float dt = fmaf(qz, pcur.z, fmaf(qy, pcur.y, qx * pcur.x));
            const float d = fmaxf(fmaf(-2.f, dt, pcur.w + qq), 0.f);
            const unsigned int key = valid ? __float_as_uint(d) : 0xFFFFFFFFu;
            bool cb[RQ];
#pragma unroll
            for (int s = 0; s < RQ; ++s) cb[s] = key < kh[s];
#pragma unroll
            for (int s = RQ - 1; s >= 1; --s) {
                kh[s] = cb[s - 1] ? kh[s - 1] : (cb[s] ? key : kh[s]);
                kl[s] = cb[s - 1] ? kl[s - 1] : (cb[s] ? (unsigned int)pos : kl[s]);
            }
            kh[0] = cb[0] ? key : kh[0];
            kl[0] = cb[0] ? (unsigned int)pos : kl[0];
            pcur = pnxt;
        }

        // ---- T = m_(kk): wave bitonic sort of the 64 lane-mins ----
        unsigned int x = kh[0];
#pragma unroll
        for (int k = 2; k <= 64; k <<= 1) {
#pragma unroll
            for (int jj = k >> 1; jj; jj >>= 1) {
                const unsigned int y = __shfl_xor(x, jj);
                const bool keepmin = (((lane & jj) == 0) == ((lane & k) == 0));
                const unsigned int mn = min(x, y), mxv = x > y ? x : y;
                x = keepmin ? mn : mxv;
            }
        }
        const float T_f = __uint_as_float(__shfl(x, kk - 1));

        // ---- phase 2: expand bins outward while edge-dz^2 can beat T ----
        int bleft = lo - 1, bright = hi;
        float dzL2 = 3.0e38f, dzR2 = 3.0e38f;
        if (bleft >= 0)  { const float dz = qz - ZB[bleft];      dzL2 = dz * dz * 0.99999f; }
        if (bright <= 63){ const float dz = ZB[bright - 1] - qz; dzR2 = dz * dz * 0.99999f; }
        bool aliveL = (bleft >= 0) && !(dzL2 > T_f);
        bool aliveR = (bright <= 63) && !(dzR2 > T_f);

        while (aliveL || aliveR) {
            const bool doR = aliveR && (!aliveL || dzR2 <= dzL2);
            const int bin = doR ? bright : bleft;
            const int bs = starts[bl * 65 + bin], be = starts[bl * 65 + bin + 1];
            for (int p0c = bs; p0c < be; p0c += 64) {
                const int pos = p0c + lane;
                const bool valid = pos < be;
                const float4 pc = L[min(pos, be - 1)];
                const float dt = fmaf(qz, pc.z, fmaf(qy, pc.y, qx * pc.x));
                const float d = fmaxf(fmaf(-2.f, dt, pc.w + qq), 0.f);
                const unsigned int key = valid ? __float_as_uint(d) : 0xFFFFFFFFu;
                bool cb[RQ];
#pragma unroll
                for (int s = 0; s < RQ; ++s) cb[s] = key < kh[s];
#pragma unroll
                for (int s = RQ - 1; s >= 1; --s) {
                    kh[s] = cb[s - 1] ? kh[s - 1] : (cb[s] ? key : kh[s]);
                    kl[s] = cb[s - 1] ? kl[s - 1] : (cb[s] ? (unsigned int)pos : kl[s]);
                }
                kh[0] = cb[0] ? key : kh[0];
                kl[0] = cb[0] ? (unsigned int)pos : kl[0];
            }
            if (doR) {
                ++bright;
                if (bright <= 63) { const float dz = ZB[bright - 1] - qz; dzR2 = dz * dz * 0.99999f; }
                aliveR = (bright <= 63) && !(dzR2 > T_f);
            } else {
                --bleft;
                if (bleft >= 0) { const float dz = qz - ZB[bleft]; dzL2 = dz * dz * 0.99999f; }
                aliveL = (bleft >= 0) && !(dzL2 > T_f);
            }
        }

        // ---- extraction: kk rounds of key wave-min + smallest-idx tiebreak ----
        unsigned int mwin = 0;
        for (int rr = 0; rr < kk; ++rr) {
            unsigned int gg = kh[0];
#pragma unroll
            for (int off = 32; off; off >>= 1) gg = min(gg, __shfl_xor(gg, off));
            const bool tied = (kh[0] == gg);
            unsigned int mc;
            const unsigned long long bal = __ballot(tied);
            if (bal & (bal - 1)) {
                mc = tied ? kl[0] : 0xFFFFFFFFu;
#pragma unroll
                for (int off = 32; off; off >>= 1) mc = min(mc, __shfl_xor(mc, off));
            } else {
                mc = __shfl(kl[0], (int)__ffsll((long long)bal) - 1);
            }
            const bool w = tied && (kl[0] == mc);
            if (lane == rr) mwin = mc;
#pragma unroll
            for (int s = 0; s < RQ - 1; ++s) {
                kh[s] = w ? kh[s + 1] : kh[s];
                kl[s] = w ? kl[s + 1] : kl[s];
            }
            kh[RQ - 1] = w ? 0xFFFFFFFFu : kh[RQ - 1];
            kl[RQ - 1] = w ? 0xFFFFFFFFu : kl[RQ - 1];
        }
        const int obase = (q << 5) + (list ? k0 : 0);
        if (lane < kk) {
            const float4 pc = L[mwin];
            const float rx = pc.x - qx, ry = pc.y - qy, rz = pc.z - qz;
            feat[obase + lane] =
                make_float4(rx, ry, rz,
                            sqrtf(fmaf(rx, rx, fmaf(ry, ry, rz * rz))));
        }
        if (list == 0 && lane == 0) newp[q] = make_float4(qx, qy, qz, 0.f);
    }
}

// ---------------------------------------------------------------------------
// K2: per-sample feature moments (S=sum f [4], M=sum f f^T [10]).
// ---------------------------------------------------------------------------
__global__ __launch_bounds__(256) void moment_stats_kernel(
    const float4* __restrict__ feat, float* __restrict__ stats1, int N)
{
    const int t = threadIdx.x, lane = t & 63;
    const int bpb = 64;
    const int b = blockIdx.x / bpb;
    const int ppb = (N * 32) / bpb;
    const size_t base = (size_t)b * N * 32 + (size_t)(blockIdx.x % bpb) * ppb;
    float a[14];
#pragma unroll
    for (int i = 0; i < 14; ++i) a[i] = 0.f;
    for (int i = t; i < ppb; i += 256) {
        const float4 f = feat[base + i];
        a[0] += f.x; a[1] += f.y; a[2] += f.z; a[3] += f.w;
        a[4] = fmaf(f.x, f.x, a[4]);  a[5] = fmaf(f.x, f.y, a[5]);
        a[6] = fmaf(f.x, f.z, a[6]);  a[7] = fmaf(f.x, f.w, a[7]);
        a[8] = fmaf(f.y, f.y, a[8]);  a[9] = fmaf(f.y, f.z, a[9]);
        a[10] = fmaf(f.y, f.w, a[10]); a[11] = fmaf(f.z, f.z, a[11]);
        a[12] = fmaf(f.z, f.w, a[12]); a[13] = fmaf(f.w, f.w, a[13]);
    }
#pragma unroll
    for (int i = 0; i < 14; ++i) {
        float x = a[i];
#pragma unroll
        for (int o = 32; o; o >>= 1) x += __shfl_down(x, o);
        a[i] = x;
    }
    __shared__ float sm[14];
    if (t < 14) sm[t] = 0.f;
    __syncthreads();
    if (lane == 0) {
#pragma unroll
        for (int i = 0; i < 14; ++i) atomicAdd(&sm[i], a[i]);
    }
    __syncthreads();
    if (t < 14) atomicAdd(&stats1[b * 14 + t], sm[t]);
}

// ---------------------------------------------------------------------------
// K3/K4: conv1+gn1+relu -> bf16 h in LDS -> conv2 via MFMA 16x16x32
// (unchanged from round 7).
// ---------------------------------------------------------------------------
template <int MODE>
__global__ __launch_bounds__(256) void conv2_pass_kernel(
    const float4* __restrict__ feat,
    const float* __restrict__ w1, const float* __restrict__ b1,
    const float* __restrict__ gn1w, const float* __restrict__ gn1b,
    const float* __restrict__ stats1,
    const float* __restrict__ w2, const float* __restrict__ b2,
    const float* __restrict__ gn2w, const float* __restrict__ gn2b,
    float* __restrict__ stats2,
    const float4* __restrict__ newp, float* __restrict__ out,
    int N, float inv_cnt)
{
    const int t = threadIdx.x, lane = t & 63, wv = t >> 6;
    const int quad = lane >> 4, col = lane & 15;
    const int bpb = (N * 32) / 512;
    const int b = blockIdx.x / bpb;
    const int pblock = (blockIdx.x - b * bpb) * 512;
    const size_t pbase = (size_t)b * N * 32 + pblock + wv * 128;

    __shared__ float sfin[24];
    __shared__ float sacc[16];
    __shared__ unsigned short h_lds[512 * 40];
    __shared__ float ssc[512];

    if (t < 16) sacc[t] = 0.f;
    if (t < 4) {
        const float cnt = (float)(N * 32);
        const float* mm = stats1 + b * 14;
        const float S0 = mm[0], S1 = mm[1], S2 = mm[2], S3 = mm[3];
        float sum = 0.f, sq = 0.f;
        for (int cch = 0; cch < 8; ++cch) {
            const int cid = t * 8 + cch;
            const float4 w = ((const float4*)w1)[cid];
            const float bb = b1[cid];
            const float ws = w.x * S0 + w.y * S1 + w.z * S2 + w.w * S3;
            const float wMw =
                w.x * w.x * mm[4] + w.y * w.y * mm[8] + w.z * w.z * mm[11] +
                w.w * w.w * mm[13] +
                2.f * (w.x * w.y * mm[5] + w.x * w.z * mm[6] + w.x * w.w * mm[7] +
                       w.y * w.z * mm[9] + w.y * w.w * mm[10] + w.z * w.w * mm[12]);
            sum += cnt * bb + ws;
            sq += cnt * bb * bb + 2.f * bb * ws + wMw;
        }
        const float mu = sum * inv_cnt, var = sq * inv_cnt - mu * mu;
        sfin[2 * t] = mu; sfin[2 * t + 1] = rsqrtf(var + 1e-5f);
    }
    if (MODE == 1 && t >= 4 && t < 12) {
        const int g = t - 4;
        const float S = stats2[b * 16 + g], Q = stats2[b * 16 + 8 + g];
        const float mu = S * inv_cnt, var = Q * inv_cnt - mu * mu;
        sfin[8 + 2 * g] = mu; sfin[8 + 2 * g + 1] = rsqrtf(var + 1e-5f);
    }
    __syncthreads();

    const int c1 = lane & 31, pt = lane >> 5;
    const float4 w1r = ((const float4*)w1)[c1];
    const float b1c = b1[c1];
    const int g1 = c1 >> 3;
    const float sc1 = sfin[2 * g1 + 1] * gn1w[c1];
    const float sh1 = gn1b[c1] - sfin[2 * g1] * sc1;

    for (int it = 0; it < 64; ++it) {
        const size_t p = pbase + it * 2;
        const float4 f = feat[p + pt];
        const float y = b1c + w1r.x * f.x + w1r.y * f.y + w1r.z * f.z + w1r.w * f.w;
        const float h = fmaxf(0.f, fmaf(y, sc1, sh1));
        h_lds[(wv * 128 + it * 2 + pt) * 40 + c1] = f2bf(h);
    }

    s8v afr[4];
#pragma unroll
    for (int T = 0; T < 4; ++T) {
        const int row = T * 16 + col;
#pragma unroll
        for (int j2 = 0; j2 < 8; ++j2)
            afr[T][j2] = (short)f2bf(w2[row * 32 + quad * 8 + j2]);
    }

    float b2v[4][4], sc2v[4][4], sh2v[4][4];
#pragma unroll
    for (int T = 0; T < 4; ++T)
#pragma unroll
        for (int r4 = 0; r4 < 4; ++r4) {
            const int cch = T * 16 + quad * 4 + r4;
            b2v[T][r4] = b2[cch];
            if (MODE == 1) {
                const int g2 = cch >> 3;
                const float sc = sfin[8 + 2 * g2 + 1] * gn2w[cch];
                sc2v[T][r4] = sc;
                sh2v[T][r4] = gn2b[cch] - sfin[8 + 2 * g2] * sc + b2[cch] * sc;
            }
        }

    float gsum[4] = {0, 0, 0, 0}, gsq[4] = {0, 0, 0, 0};

    for (int pt16 = 0; pt16 < 8; ++pt16) {
        const int row = wv * 128 + pt16 * 16 + col;
        const s8v bfr = *(const s8v*)&h_lds[row * 40 + quad * 8];
        f32x4 acc[4];
#pragma unroll
        for (int T = 0; T < 4; ++T) {
            acc[T] = (f32x4){0.f, 0.f, 0.f, 0.f};
            acc[T] = __builtin_amdgcn_mfma_f32_16x16x32_bf16(afr[T], bfr, acc[T], 0, 0, 0);
        }
        if (MODE == 0) {
#pragma unroll
            for (int T = 0; T < 4; ++T)
#pragma unroll
                for (int r4 = 0; r4 < 4; ++r4) {
                    const float v = acc[T][r4] + b2v[T][r4];
                    gsum[T] += v;
                    gsq[T] = fmaf(v, v, gsq[T]);
                }
        } else {
            float s = -3.0e38f;
#pragma unroll
            for (int T = 0; T < 4; ++T)
#pragma unroll
                for (int r4 = 0; r4 < 4; ++r4)
                    s = fmaxf(s, fmaxf(0.f, fmaf(acc[T][r4], sc2v[T][r4], sh2v[T][r4])));
            s = fmaxf(s, __shfl_xor(s, 16));
            s = fmaxf(s, __shfl_xor(s, 32));
            if (quad == 0) ssc[wv * 128 + pt16 * 16 + col] = s;
        }
    }

    if (MODE == 0) {
#pragma unroll
        for (int T = 0; T < 4; ++T) {
#pragma unroll
            for (int o = 1; o < 16; o <<= 1) {
                gsum[T] += __shfl_xor(gsum[T], o);
                gsq[T] += __shfl_xor(gsq[T], o);
            }
            gsum[T] += __shfl_xor(gsum[T], 16);
            gsq[T] += __shfl_xor(gsq[T], 16);
        }
        if (lane == 0) {
#pragma unroll
            for (int T = 0; T < 4; ++T) {
                atomicAdd(&sacc[2 * T], gsum[T]);
                atomicAdd(&sacc[8 + 2 * T], gsq[T]);
            }
        }
        if (lane == 32) {
#pragma unroll
            for (int T = 0; T < 4; ++T) {
                atomicAdd(&sacc[2 * T + 1], gsum[T]);
                atomicAdd(&sacc[8 + 2 * T + 1], gsq[T]);
            }
        }
        __syncthreads();
        if (t < 16) atomicAdd(&stats2[b * 16 + t], sacc[t]);
    } else {
        __syncthreads();
        const int qi = t >> 4, sub = t & 15;
        const int qg = (b * N * 32 + pblock) / 32 + qi;
        const int n = qg - b * N;
        const float s0 = ssc[qi * 32 + sub], s1 = ssc[qi * 32 + 16 + sub];
        float mx = fmaxf(s0, s1);
#pragma unroll
        for (int o = 8; o; o >>= 1) mx = fmaxf(mx, __shfl_xor(mx, o));
        const float e0 = __expf(s0 - mx), e1 = __expf(s1 - mx);
        float ssum = e0 + e1;
#pragma unroll
        for (int o = 8; o; o >>= 1) ssum += __shfl_xor(ssum, o);
        const float4 qc = newp[qg];
        const float4 f0 = feat[(size_t)qg * 32 + sub];
        const float4 f1 = feat[(size_t)qg * 32 + 16 + sub];
        float ax = e0 * (qc.x + f0.x) + e1 * (qc.x + f1.x);
        float ay = e0 * (qc.y + f0.y) + e1 * (qc.y + f1.y);
        float az = e0 * (qc.z + f0.z) + e1 * (qc.z + f1.z);
#pragma unroll
        for (int o = 8; o; o >>= 1) {
            ax += __shfl_xor(ax, o);
            ay += __shfl_xor(ay, o);
            az += __shfl_xor(az, o);
        }
        if (sub == 0) {
            const float inv = 1.f / ssum;
            out[(b * 3 + 0) * N + n] = ax * inv;
            out[(b * 3 + 1) * N + n] = ay * inv;
            out[(b * 3 + 2) * N + n] = az * inv;
        }
    }
}

// ---------------------------------------------------------------------------
extern "C" void kernel_launch(void* const* d_in, const int* in_sizes, int n_in,
                              void* d_out, int out_size, void* d_ws, size_t ws_size,
                              hipStream_t stream)
{
    const float* p0   = (const float*)d_in[0];
    const float* p1   = (const float*)d_in[1];
    const float* wt   = (const float*)d_in[3];
    const int*   perm = (const int*)d_in[4];
    const float* w1   = (const float*)d_in[5];
    const float* b1   = (const float*)d_in[6];
    const float* gn1w = (const float*)d_in[7];
    const float* gn1b = (const float*)d_in[8];
    const float* w2   = (const float*)d_in[9];
    const float* b2   = (const float*)d_in[10];
    const float* gn2w = (const float*)d_in[11];
    const float* gn2b = (const float*)d_in[12];
    float* out = (float*)d_out;

    const int B = in_sizes[3] / 2;
    const int N = in_sizes[0] / (3 * B);

    // workspace layout
    char* ws = (char*)d_ws;
    float4* spts = (float4*)ws;               // B*2*4096 float4 (z-binned CSR)
    size_t off = (size_t)B * 2 * 4096 * sizeof(float4);
    float4* feat = (float4*)(ws + off);       off += (size_t)B * N * 32 * sizeof(float4);
    float4* newp = (float4*)(ws + off);       off += (size_t)B * N * sizeof(float4);
    float* stats1 = (float*)(ws + off);       off += (size_t)B * 14 * sizeof(float);
    float* stats2 = (float*)(ws + off);       off += (size_t)B * 16 * sizeof(float);
    int* starts = (int*)(ws + off);           // B*2*65 CSR offsets

    hipMemsetAsync(stats1, 0, (size_t)B * 30 * sizeof(float), stream);

    const float inv_cnt = 1.f / (8.f * (float)N * 32.f);

    zbin_kernel<<<B * 2, 1024, 0, stream>>>(p0, p1, spts, starts, N);

    knn_kernel<<<(B * 2 * N) / (4 * TPW), 256, 0, stream>>>(
        p0, p1, wt, perm, spts, starts, feat, newp, N);

    moment_stats_kernel<<<B * 64, 256, 0, stream>>>(feat, stats1, N);

    conv2_pass_kernel<0><<<(B * N * 32) / 512, 256, 0, stream>>>(
        feat, w1, b1, gn1w, gn1b, stats1, w2, b2, gn2w, gn2b, stats2,
        newp, out, N, inv_cnt);

    conv2_pass_kernel<1><<<(B * N * 32) / 512, 256, 0, stream>>>(
        feat, w1, b1, gn1w, gn1b, stats1, w2, b2, gn2w, gn2b, stats2,
        newp, out, N, inv_cnt);
}